// Round 1
// baseline (4469.661 us; speedup 1.0000x reference)
//
#include <hip/hip_runtime.h>
#include <math.h>

// Problem constants (reference: B,H,S,D = 4,16,1024,64)
#define BB 4
#define HH 16
#define SS 1024
#define DD 64

constexpr int QT = 64;        // q rows per block
constexpr int KT = 128;       // k rows per LDS tile
constexpr int NKT = SS / KT;  // 8 tiles
constexpr int THREADS = 256;
constexpr int WAVES = 4;
constexpr int RPW = QT / WAVES;  // 16 q-rows per wave
constexpr int STRIDE = 68;       // padded fp32 row stride: 17 float4 -> 8 dwords/bank (optimal)

__device__ __forceinline__ float4 ld4(const float* p) {
    return *reinterpret_cast<const float4*>(p);
}
__device__ __forceinline__ void st4(float* p, float4 v) {
    *reinterpret_cast<float4*>(p) = v;
}

// Kernel A: per (b,h,q-tile) block — compute w[k] = sum_q softmax(QK^T)[q,k]
__global__ __launch_bounds__(THREADS, 2)
void attn_colsum_kernel(const float* __restrict__ Q,
                        const float* __restrict__ K,
                        const int* __restrict__ mask,
                        float* __restrict__ w) {
    __shared__ float q_lds[QT * STRIDE];      // 17408 B
    __shared__ float k_lds[KT * STRIDE];      // 34816 B
    __shared__ float w_lds[WAVES][SS];        // 16384 B

    const int bid = blockIdx.x;
    const int nqt = SS / QT;                  // 16
    const int qt  = bid % nqt;
    const int bh  = bid / nqt;                // 0..63
    const int b   = bh / HH;
    const int tid  = threadIdx.x;
    const int wave = tid >> 6;
    const int lane = tid & 63;

    const float scale = 0.125f;               // 1/sqrt(64)
    const float* Qbh = Q + (size_t)bh * SS * DD;
    const float* Kbh = K + (size_t)bh * SS * DD;
    const int q0 = qt * QT;
    const int wrow = wave * RPW;

    // ---- stage Q tile (scaled) ----
    {
        const int row = tid >> 4;             // 16 threads per 64-float row
        const int c   = (tid & 15) * 4;
        #pragma unroll
        for (int rr = 0; rr < QT; rr += 16) {
            float4 v = ld4(Qbh + (size_t)(q0 + row + rr) * DD + c);
            v.x *= scale; v.y *= scale; v.z *= scale; v.w *= scale;
            st4(&q_lds[(row + rr) * STRIDE + c], v);
        }
    }

    float l_lane[RPW];
    #pragma unroll
    for (int r = 0; r < RPW; ++r) l_lane[r] = 0.0f;

    // =================== PASS 1: row exp-sums ===================
    for (int t = 0; t < NKT; ++t) {
        __syncthreads();   // protect previous tile (and Q staging on t==0)
        {
            const int row = tid >> 4;
            const int c   = (tid & 15) * 4;
            #pragma unroll
            for (int rr = 0; rr < KT; rr += 16) {
                float4 v = ld4(Kbh + (size_t)(t * KT + row + rr) * DD + c);
                st4(&k_lds[(row + rr) * STRIDE + c], v);
            }
        }
        __syncthreads();

        float acc0[RPW], acc1[RPW];
        #pragma unroll
        for (int r = 0; r < RPW; ++r) { acc0[r] = 0.0f; acc1[r] = 0.0f; }

        #pragma unroll
        for (int dc = 0; dc < DD; dc += 4) {
            const float4 kv0 = ld4(&k_lds[lane * STRIDE + dc]);
            const float4 kv1 = ld4(&k_lds[(lane + 64) * STRIDE + dc]);
            #pragma unroll
            for (int r = 0; r < RPW; ++r) {
                const float4 qv = ld4(&q_lds[(wrow + r) * STRIDE + dc]);
                acc0[r] = fmaf(qv.x, kv0.x, acc0[r]);
                acc0[r] = fmaf(qv.y, kv0.y, acc0[r]);
                acc0[r] = fmaf(qv.z, kv0.z, acc0[r]);
                acc0[r] = fmaf(qv.w, kv0.w, acc0[r]);
                acc1[r] = fmaf(qv.x, kv1.x, acc1[r]);
                acc1[r] = fmaf(qv.y, kv1.y, acc1[r]);
                acc1[r] = fmaf(qv.z, kv1.z, acc1[r]);
                acc1[r] = fmaf(qv.w, kv1.w, acc1[r]);
            }
        }

        #pragma unroll
        for (int r = 0; r < RPW; ++r) {
            const int q = q0 + wrow + r;
            const int* mrow = mask + ((size_t)b * SS + q) * SS + t * KT;
            const int m0 = mrow[lane];
            const int m1 = mrow[lane + 64];
            const float e0 = m0 ? __expf(acc0[r]) : 0.0f;
            const float e1 = m1 ? __expf(acc1[r]) : 0.0f;
            l_lane[r] += e0 + e1;
        }
    }

    // wave-reduce l per row -> 1/l
    float invl[RPW];
    #pragma unroll
    for (int r = 0; r < RPW; ++r) {
        float v = l_lane[r];
        #pragma unroll
        for (int off = 32; off >= 1; off >>= 1) v += __shfl_xor(v, off);
        invl[r] = 1.0f / v;
    }

    // =================== PASS 2: column-sum accumulation ===================
    for (int t = 0; t < NKT; ++t) {
        __syncthreads();
        {
            const int row = tid >> 4;
            const int c   = (tid & 15) * 4;
            #pragma unroll
            for (int rr = 0; rr < KT; rr += 16) {
                float4 v = ld4(Kbh + (size_t)(t * KT + row + rr) * DD + c);
                st4(&k_lds[(row + rr) * STRIDE + c], v);
            }
        }
        __syncthreads();

        float acc0[RPW], acc1[RPW];
        #pragma unroll
        for (int r = 0; r < RPW; ++r) { acc0[r] = 0.0f; acc1[r] = 0.0f; }

        #pragma unroll
        for (int dc = 0; dc < DD; dc += 4) {
            const float4 kv0 = ld4(&k_lds[lane * STRIDE + dc]);
            const float4 kv1 = ld4(&k_lds[(lane + 64) * STRIDE + dc]);
            #pragma unroll
            for (int r = 0; r < RPW; ++r) {
                const float4 qv = ld4(&q_lds[(wrow + r) * STRIDE + dc]);
                acc0[r] = fmaf(qv.x, kv0.x, acc0[r]);
                acc0[r] = fmaf(qv.y, kv0.y, acc0[r]);
                acc0[r] = fmaf(qv.z, kv0.z, acc0[r]);
                acc0[r] = fmaf(qv.w, kv0.w, acc0[r]);
                acc1[r] = fmaf(qv.x, kv1.x, acc1[r]);
                acc1[r] = fmaf(qv.y, kv1.y, acc1[r]);
                acc1[r] = fmaf(qv.z, kv1.z, acc1[r]);
                acc1[r] = fmaf(qv.w, kv1.w, acc1[r]);
            }
        }

        float w0 = 0.0f, w1 = 0.0f;
        #pragma unroll
        for (int r = 0; r < RPW; ++r) {
            const int q = q0 + wrow + r;
            const int* mrow = mask + ((size_t)b * SS + q) * SS + t * KT;
            const int m0 = mrow[lane];
            const int m1 = mrow[lane + 64];
            if (m0) w0 += __expf(acc0[r]) * invl[r];
            if (m1) w1 += __expf(acc1[r]) * invl[r];
        }
        // each (wave, k) is written exactly once across the t loop
        w_lds[wave][t * KT + lane]      = w0;
        w_lds[wave][t * KT + 64 + lane] = w1;
    }

    __syncthreads();
    for (int k = tid; k < SS; k += THREADS) {
        const float v = w_lds[0][k] + w_lds[1][k] + w_lds[2][k] + w_lds[3][k];
        atomicAdd(&w[(size_t)bh * SS + k], v);
    }
}

// Kernel B: out[bh, d] = sum_k w[bh,k] * V[bh,k,d]
__global__ __launch_bounds__(THREADS)
void attn_out_kernel(const float* __restrict__ w,
                     const float* __restrict__ V,
                     float* __restrict__ out) {
    const int bh  = blockIdx.x;
    const int tid = threadIdx.x;
    const int d   = tid & 63;
    const int kg  = tid >> 6;   // 4 k-groups
    const float* Vbh = V + (size_t)bh * SS * DD;
    const float* wbh = w + (size_t)bh * SS;

    float acc = 0.0f;
    for (int k = kg; k < SS; k += 4)
        acc = fmaf(wbh[k], Vbh[(size_t)k * DD + d], acc);

    __shared__ float red[4][64];
    red[kg][d] = acc;
    __syncthreads();
    if (kg == 0)
        out[(size_t)bh * DD + d] = red[0][d] + red[1][d] + red[2][d] + red[3][d];
}

extern "C" void kernel_launch(void* const* d_in, const int* in_sizes, int n_in,
                              void* d_out, int out_size, void* d_ws, size_t ws_size,
                              hipStream_t stream) {
    const float* Q    = (const float*)d_in[0];
    const float* K    = (const float*)d_in[1];
    const float* V    = (const float*)d_in[2];
    const int*   mask = (const int*)d_in[3];
    float* out = (float*)d_out;
    float* w   = (float*)d_ws;   // B*H*S floats = 256 KiB

    hipMemsetAsync(w, 0, (size_t)BB * HH * SS * sizeof(float), stream);

    dim3 gridA(BB * HH * (SS / QT));   // 1024 blocks
    attn_colsum_kernel<<<gridA, THREADS, 0, stream>>>(Q, K, mask, w);

    dim3 gridB(BB * HH);               // 64 blocks
    attn_out_kernel<<<gridB, THREADS, 0, stream>>>(w, V, out);
}

// Round 5
// 327.846 us; speedup vs baseline: 13.6334x; 13.6334x over previous
//
#include <hip/hip_runtime.h>
#include <hip/hip_bf16.h>
#include <math.h>

// B,H,S,D = 4,16,1024,64 ; out[b,h,d] = sum_q (softmax(QK^T/sqrt(D)) @ V)[q,d]
//                                     = sum_k w[k]*V[k,d],  w[k] = sum_q attn[q,k]
#define BB 4
#define HH 16
#define SS 1024
#define DD 64

typedef __attribute__((ext_vector_type(8))) short bf16x8;
typedef __attribute__((ext_vector_type(4))) float f32x4;

#define MFMA_BF16 __builtin_amdgcn_mfma_f32_16x16x32_bf16

__device__ __forceinline__ float4 ld4f(const float* p) {
    return *reinterpret_cast<const float4*>(p);
}

// split fp32 x into bf16 hi + bf16 lo (x ~= hi + lo, |lo| <= 2^-9 |x|)
__device__ __forceinline__ void bsplit(float x, short& h, short& l) {
    __hip_bfloat16 bh = __float2bfloat16(x);
    float rem = x - __bfloat162float(bh);
    __hip_bfloat16 bl = __float2bfloat16(rem);
    h = *reinterpret_cast<short*>(&bh);
    l = *reinterpret_cast<short*>(&bl);
}

// prep: K fp32 -> Kh, Kl bf16 arrays (workspace)
__global__ __launch_bounds__(256)
void split_kernel(const float* __restrict__ in, short* __restrict__ hi,
                  short* __restrict__ lo, int n4) {
    const float4* in4 = reinterpret_cast<const float4*>(in);
    for (int i = blockIdx.x * blockDim.x + threadIdx.x; i < n4;
         i += gridDim.x * blockDim.x) {
        float4 v = in4[i];
        short h0, h1, h2, h3, l0, l1, l2, l3;
        bsplit(v.x, h0, l0); bsplit(v.y, h1, l1);
        bsplit(v.z, h2, l2); bsplit(v.w, h3, l3);
        short4 hv = {h0, h1, h2, h3};
        short4 lv = {l0, l1, l2, l3};
        reinterpret_cast<short4*>(hi)[i] = hv;
        reinterpret_cast<short4*>(lo)[i] = lv;
    }
}

constexpr int QT = 128;  // q rows per block; 4 waves x 2 subtiles of 16

// PRESPLIT=true : K fragments from pre-split bf16 hi/lo arrays in workspace.
// PRESPLIT=false: K fragments split from fp32 in registers (no workspace).
template <bool PRESPLIT>
__global__ __launch_bounds__(256, 2)
void attn_mfma(const float* __restrict__ Q, const short* __restrict__ Kh,
               const short* __restrict__ Kl, const float* __restrict__ Kf,
               const float* __restrict__ V, const int* __restrict__ mask,
               float* __restrict__ out) {
    __shared__ float w_lds[4][SS];   // per-wave column sums, 16 KB
    __shared__ float red[4][64];

    const int bid = blockIdx.x;
    const int nqt = SS / QT;              // 8
    const int qt  = bid % nqt;
    const int bh  = bid / nqt;            // 0..63
    const int b   = bh / HH;
    const int tid  = threadIdx.x;
    const int wave = tid >> 6;
    const int lane = tid & 63;
    const int lg = lane >> 4;             // k-group / row-quarter
    const int lr = lane & 15;             // A row / B col within tile

    const size_t bhoff = (size_t)bh * SS * DD;
    const int q0 = qt * QT;
    const int m_base = q0 + wave * 32;    // this wave's 32 q rows

    // ---- preload Q fragments (scaled by 1/sqrt(D), split hi/lo) ----
    bf16x8 qh00, qh01, qh10, qh11, ql00, ql01, ql10, ql11;
    {
        auto loadq = [&](int s, int d, bf16x8& H, bf16x8& L) {
            const float* qp = Q + bhoff + (size_t)(m_base + s * 16 + lr) * DD
                              + d * 32 + lg * 8;
            float4 a = ld4f(qp), c = ld4f(qp + 4);
            float xs[8] = {a.x, a.y, a.z, a.w, c.x, c.y, c.z, c.w};
            #pragma unroll
            for (int j = 0; j < 8; ++j) {
                short hh, ll;
                bsplit(xs[j] * 0.125f, hh, ll);
                H[j] = hh; L[j] = ll;
            }
        };
        loadq(0, 0, qh00, ql00); loadq(0, 1, qh01, ql01);
        loadq(1, 0, qh10, ql10); loadq(1, 1, qh11, ql11);
    }

    // mask row base offsets: row = m_base + s*16 + lg*4 + r, col base = lr
    int moff[2][4];
    #pragma unroll
    for (int s = 0; s < 2; ++s)
        #pragma unroll
        for (int r = 0; r < 4; ++r)
            moff[s][r] = (b * SS + m_base + s * 16 + lg * 4 + r) * SS + lr;

    const short* khp = Kh + bhoff + (size_t)lr * DD + lg * 8;
    const short* klp = Kl + bhoff + (size_t)lr * DD + lg * 8;
    const float* kfp = Kf + bhoff + (size_t)lr * DD + lg * 8;

    // load K fragments for 16-col tile at n0 (hi/lo, two K=32 d-steps)
    auto load_k = [&](int n0, bf16x8& kh0, bf16x8& kh1, bf16x8& kl0,
                      bf16x8& kl1) {
        if constexpr (PRESPLIT) {
            const short* kp = khp + (size_t)n0 * DD;
            kh0 = *(const bf16x8*)kp;
            kh1 = *(const bf16x8*)(kp + 32);
            const short* lp = klp + (size_t)n0 * DD;
            kl0 = *(const bf16x8*)lp;
            kl1 = *(const bf16x8*)(lp + 32);
        } else {
            const float* kp = kfp + (size_t)n0 * DD;
            float4 a = ld4f(kp), c = ld4f(kp + 4);
            float4 e = ld4f(kp + 32), g = ld4f(kp + 36);
            float x0[8] = {a.x, a.y, a.z, a.w, c.x, c.y, c.z, c.w};
            float x1[8] = {e.x, e.y, e.z, e.w, g.x, g.y, g.z, g.w};
            #pragma unroll
            for (int j = 0; j < 8; ++j) {
                short hh, ll;
                bsplit(x0[j], hh, ll);
                kh0[j] = hh; kl0[j] = ll;
                bsplit(x1[j], hh, ll);
                kh1[j] = hh; kl1[j] = ll;
            }
        }
    };

    auto qk_tile = [&](int n0, f32x4& acc0, f32x4& acc1) {
        bf16x8 kh0, kh1, kl0, kl1;
        load_k(n0, kh0, kh1, kl0, kl1);
        acc0 = MFMA_BF16(qh00, kh0, acc0, 0, 0, 0);
        acc0 = MFMA_BF16(qh01, kh1, acc0, 0, 0, 0);
        acc0 = MFMA_BF16(qh00, kl0, acc0, 0, 0, 0);
        acc0 = MFMA_BF16(qh01, kl1, acc0, 0, 0, 0);
        acc0 = MFMA_BF16(ql00, kh0, acc0, 0, 0, 0);
        acc0 = MFMA_BF16(ql01, kh1, acc0, 0, 0, 0);
        acc1 = MFMA_BF16(qh10, kh0, acc1, 0, 0, 0);
        acc1 = MFMA_BF16(qh11, kh1, acc1, 0, 0, 0);
        acc1 = MFMA_BF16(qh10, kl0, acc1, 0, 0, 0);
        acc1 = MFMA_BF16(qh11, kl1, acc1, 0, 0, 0);
        acc1 = MFMA_BF16(ql10, kh0, acc1, 0, 0, 0);
        acc1 = MFMA_BF16(ql11, kh1, acc1, 0, 0, 0);
    };

    // =============== PASS 1: row exp-sums l[q] ===============
    float lacc[2][4];
    #pragma unroll
    for (int s = 0; s < 2; ++s)
        #pragma unroll
        for (int r = 0; r < 4; ++r) lacc[s][r] = 0.0f;

    for (int n0 = 0; n0 < SS; n0 += 16) {
        f32x4 acc0 = {0.f, 0.f, 0.f, 0.f};
        f32x4 acc1 = {0.f, 0.f, 0.f, 0.f};
        qk_tile(n0, acc0, acc1);
        #pragma unroll
        for (int s = 0; s < 2; ++s)
            #pragma unroll
            for (int r = 0; r < 4; ++r) {
                const int m = mask[moff[s][r] + n0];
                const float sc = (s == 0) ? acc0[r] : acc1[r];
                lacc[s][r] += m ? __expf(sc) : 0.0f;
            }
    }

    // reduce over the 16 col-lanes (same lg group) -> 1/l per row
    float invl[2][4];
    #pragma unroll
    for (int s = 0; s < 2; ++s)
        #pragma unroll
        for (int r = 0; r < 4; ++r) {
            float v = lacc[s][r];
            v += __shfl_xor(v, 1);
            v += __shfl_xor(v, 2);
            v += __shfl_xor(v, 4);
            v += __shfl_xor(v, 8);
            invl[s][r] = 1.0f / v;
        }

    // =============== PASS 2: w[col] = sum_q attn[q,col] ===============
    for (int n0 = 0; n0 < SS; n0 += 16) {
        f32x4 acc0 = {0.f, 0.f, 0.f, 0.f};
        f32x4 acc1 = {0.f, 0.f, 0.f, 0.f};
        qk_tile(n0, acc0, acc1);
        float wp = 0.0f;
        #pragma unroll
        for (int s = 0; s < 2; ++s)
            #pragma unroll
            for (int r = 0; r < 4; ++r) {
                const int m = mask[moff[s][r] + n0];
                const float sc = (s == 0) ? acc0[r] : acc1[r];
                wp += m ? __expf(sc) * invl[s][r] : 0.0f;
            }
        // sum over the 4 row-quarter groups -> full 32-row contribution
        wp += __shfl_xor(wp, 16);
        wp += __shfl_xor(wp, 32);
        if (lane < 16) w_lds[wave][n0 + lr] = wp;
    }
    __syncthreads();

    // combine 4 waves' w, then out[d] += sum_c w[c] * V[c][d]
    for (int c = tid; c < SS; c += 256)
        w_lds[0][c] = w_lds[0][c] + w_lds[1][c] + w_lds[2][c] + w_lds[3][c];
    __syncthreads();

    const int d  = tid & 63;
    const int kg = tid >> 6;
    float oacc = 0.0f;
    for (int c = kg; c < SS; c += 4)
        oacc = fmaf(w_lds[0][c], V[bhoff + (size_t)c * DD + d], oacc);
    red[kg][d] = oacc;
    __syncthreads();
    if (kg == 0)
        atomicAdd(&out[bh * DD + d], red[0][d] + red[1][d] + red[2][d] + red[3][d]);
}

extern "C" void kernel_launch(void* const* d_in, const int* in_sizes, int n_in,
                              void* d_out, int out_size, void* d_ws, size_t ws_size,
                              hipStream_t stream) {
    const float* Q    = (const float*)d_in[0];
    const float* K    = (const float*)d_in[1];
    const float* V    = (const float*)d_in[2];
    const int*   mask = (const int*)d_in[3];
    float* out = (float*)d_out;

    const size_t nelem = (size_t)BB * HH * SS * DD;        // 4.19M
    const size_t need  = 2 * nelem * sizeof(short);        // 16.8 MB

    hipMemsetAsync(out, 0, (size_t)BB * HH * DD * sizeof(float), stream);

    const dim3 grid(BB * HH * (SS / QT));                  // 512 blocks

    if (ws_size >= need) {
        short* Kh = (short*)d_ws;
        short* Kl = Kh + nelem;
        split_kernel<<<1024, 256, 0, stream>>>(K, Kh, Kl, (int)(nelem / 4));
        attn_mfma<true><<<grid, 256, 0, stream>>>(Q, Kh, Kl, K, V, mask, out);
    } else {
        // workspace too small: split K in-register (no workspace needed)
        attn_mfma<false><<<grid, 256, 0, stream>>>(Q, nullptr, nullptr, K, V,
                                                   mask, out);
    }
}